// Round 13
// baseline (288.941 us; speedup 1.0000x reference)
//
#include <hip/hip_runtime.h>
#include <hip/hip_bf16.h>

#define B_    4
#define NUM   1024
#define CH    256
#define HEADS 4
#define DK    64
#define LDK   72    // padded LDS row stride in bf16 elements (2-way bank alias = free)
#define NJC   4     // apply j-chunks (256 cols each) -- atomic-cost-optimal
#define TKNJC 8     // topk j-chunks (128 cols each) -- occupancy-optimal, no atomics

typedef __hip_bfloat16 bf;
typedef __attribute__((ext_vector_type(8))) short short8;
typedef __attribute__((ext_vector_type(4))) float f32x4;
typedef unsigned long long u64;

__device__ inline bf tobf(float v) { return __float2bfloat16(v); }

// stage a 64x64 fp32 global tile -> bf16 LDS tile [64][LDK]
__device__ inline void stage_tile(const float* __restrict__ src, size_t row0,
                                  int col0, int rowstride, bf (*dst)[LDK], int tid) {
  int r = tid >> 4, c4 = (tid & 15) * 4;
  #pragma unroll
  for (int it = 0; it < 4; ++it) {
    int row = r + it * 16;
    const float4 v = *(const float4*)&src[(row0 + row) * (size_t)rowstride + col0 + c4];
    union { bf h4[4]; short4 s4; } u;
    u.h4[0] = tobf(v.x); u.h4[1] = tobf(v.y); u.h4[2] = tobf(v.z); u.h4[3] = tobf(v.w);
    *(short4*)&dst[row][c4] = u.s4;
  }
}

// load this lane's A-fragments (2 k-blocks) straight from global into registers
__device__ inline void load_afrag(const float* __restrict__ arow, int quad, short8 af[2]) {
  #pragma unroll
  for (int kb = 0; kb < 2; ++kb) {
    const float4 v0 = *(const float4*)&arow[kb * 32 + quad * 8];
    const float4 v1 = *(const float4*)&arow[kb * 32 + quad * 8 + 4];
    union { bf hh[8]; short8 s; } u;
    u.hh[0] = tobf(v0.x); u.hh[1] = tobf(v0.y); u.hh[2] = tobf(v0.z); u.hh[3] = tobf(v0.w);
    u.hh[4] = tobf(v1.x); u.hh[5] = tobf(v1.y); u.hh[6] = tobf(v1.z); u.hh[7] = tobf(v1.w);
    af[kb] = u.s;
  }
}

// ---------------- conv body: grouped 1x1 conv + relu, dual write + rn ----------------
__device__ inline void conv_body(
    char* SM, int m0, int g, int tid,
    const float* __restrict__ x, const float* __restrict__ w,
    const float* __restrict__ bias, const int* __restrict__ smask,
    float seedbase, float* __restrict__ out, float* __restrict__ out2,
    float* __restrict__ rn) {
  float (*Xs)[65] = (float(*)[65])SM;
  float (*Wsm)[65] = (float(*)[65])(SM + 16640);
  const int tx = tid & 15, ty = tid >> 4;
  #pragma unroll
  for (int l = 0; l < 16; ++l) {
    int idx = tid + l * 256; int r = idx >> 6, c = idx & 63;
    Xs[r][c] = x[(size_t)(m0 + r) * CH + g * DK + c];
    Wsm[r][c] = w[g * DK * DK + r * DK + c];
  }
  __syncthreads();
  {  // fused reciprocal norms: 4 lanes per row, 16 channels each
    int wv = tid >> 6, lane = tid & 63;
    int row = wv * 16 + (lane >> 2), part = lane & 3;
    float s = 0.f;
    #pragma unroll
    for (int k = 0; k < 16; ++k) {
      float v = Xs[row][part * 16 + k];
      s += v * v;
    }
    s += __shfl_xor(s, 1, 64);
    s += __shfl_xor(s, 2, 64);
    if (part == 0)
      rn[(size_t)(m0 + row) * HEADS + g] = 1.0f / fmaxf(sqrtf(s), 1e-4f);
  }
  float acc[4][4] = {};
  #pragma unroll 8
  for (int k = 0; k < DK; ++k) {
    float av[4], bv[4];
    #pragma unroll
    for (int i = 0; i < 4; ++i) av[i] = Xs[ty * 4 + i][k];
    #pragma unroll
    for (int j = 0; j < 4; ++j) bv[j] = Wsm[tx * 4 + j][k];
    #pragma unroll
    for (int i = 0; i < 4; ++i)
      #pragma unroll
      for (int j = 0; j < 4; ++j) acc[i][j] += av[i] * bv[j];
  }
  #pragma unroll
  for (int i = 0; i < 4; ++i) {
    int row = m0 + ty * 4 + i;
    float seed = seedbase + ((smask[row] == 0) ? 0.25f : 0.f);
    #pragma unroll
    for (int j = 0; j < 4; ++j) {
      int o = g * DK + tx * 4 + j;
      size_t idx = (size_t)row * CH + o;
      float v = fmaxf(acc[i][j] + bias[o], 0.f);
      out[idx] = v;
      out2[idx] = v * seed;
    }
  }
}

// ---------------- gts body: relu(gt_feat @ gt_w^T + gt_b), bf16 MFMA ----------------
__device__ inline void gts_body(
    char* SM, int m0, int n0, int tid,
    const float* __restrict__ gf, const float* __restrict__ gw,
    const float* __restrict__ gb, float* __restrict__ out) {
  bf (*As)[LDK] = (bf(*)[LDK])SM;
  bf (*Bs)[LDK] = (bf(*)[LDK])(SM + 9216);
  const int lane = tid & 63, w = tid >> 6;
  const int m = lane & 15, quad = lane >> 4;
  f32x4 acc[4] = {{0.f,0.f,0.f,0.f},{0.f,0.f,0.f,0.f},{0.f,0.f,0.f,0.f},{0.f,0.f,0.f,0.f}};
  for (int k0 = 0; k0 < 256; k0 += 64) {
    __syncthreads();
    stage_tile(gf, m0, k0, 256, As, tid);
    stage_tile(gw, n0, k0, 256, Bs, tid);
    __syncthreads();
    #pragma unroll
    for (int kb = 0; kb < 2; ++kb) {
      short8 a = *(const short8*)&As[w * 16 + m][kb * 32 + quad * 8];
      #pragma unroll
      for (int nt = 0; nt < 4; ++nt) {
        short8 bb = *(const short8*)&Bs[nt * 16 + m][kb * 32 + quad * 8];
        acc[nt] = __builtin_amdgcn_mfma_f32_16x16x32_bf16(a, bb, acc[nt], 0, 0, 0);
      }
    }
  }
  #pragma unroll
  for (int nt = 0; nt < 4; ++nt)
    #pragma unroll
    for (int r = 0; r < 4; ++r) {
      int row = m0 + w * 16 + quad * 4 + r, col = n0 + nt * 16 + m;
      out[(size_t)row * 256 + col] = fmaxf(acc[nt][r] + gb[col], 0.f);
    }
}

// ================ mega head kernel: conv1 (y<4) | gts (y 4..7) | pack (y 8..23) ================
__global__ __launch_bounds__(256) void head_kernel(
    const float* __restrict__ x, const float* __restrict__ w1,
    const float* __restrict__ b1, const int* __restrict__ smask,
    float* __restrict__ X1, float* __restrict__ F1, float* __restrict__ rn,
    const float* __restrict__ gf, const float* __restrict__ gw,
    const float* __restrict__ gb, float* __restrict__ gts_out,
    const int* __restrict__ mroi, u64* __restrict__ pk,
    float* __restrict__ v1, float* __restrict__ v2) {
  __shared__ __align__(16) char SM[33280];
  const int tid = threadIdx.x;
  if (blockIdx.y < 4) {
    conv_body(SM, blockIdx.x * 64, blockIdx.y, tid, x, w1, b1, smask, 1.0f, X1, F1, rn);
  } else if (blockIdx.y < 8) {
    gts_body(SM, blockIdx.x * 64, (blockIdx.y - 4) * 64, tid, gf, gw, gb, gts_out);
  } else {
    int blkrow = (blockIdx.y - 8) * 64 + blockIdx.x;   // 0..1023
    if (blkrow < 4) {
      int i = blkrow * 256 + tid;
      v1[i] = 0.f; v2[i] = 0.f;
    }
    int row = blkrow * 4 + (tid >> 6);
    int lane = tid & 63;
    int b = row >> 10;
    const int* mr = &mroi[(size_t)row * NUM];
    const int* sm = &smask[b * NUM];
    #pragma unroll
    for (int wd = 0; wd < 16; ++wd) {
      int j = wd * 64 + lane;
      u64 word = __ballot((mr[j] != 0) && (sm[j] != 0));
      if (lane == 0) pk[(size_t)row * 16 + wd] = word;
    }
  }
}

// ---------------- grouped 1x1 conv + relu (fp32) standalone (stage 2) ----------------
__global__ __launch_bounds__(256) void conv_kernel(
    const float* __restrict__ x, const float* __restrict__ w,
    const float* __restrict__ bias, const int* __restrict__ smask,
    float seedbase, float* __restrict__ out, float* __restrict__ out2,
    float* __restrict__ rn) {
  __shared__ __align__(16) char SM[33280];
  conv_body(SM, blockIdx.x * 64, blockIdx.y, threadIdx.x, x, w, bias, smask,
            seedbase, out, out2, rn);
}

// top-4 insert, jax-stable tie-break (higher value first; equal value -> lower index)
__device__ inline void ins4(float v, int id, float tv[4], int tj[4]) {
  if (v < tv[3] || (v == tv[3] && id > tj[3])) return;
  tv[3] = v; tj[3] = id;
  #pragma unroll
  for (int k = 3; k > 0; --k) {
    bool sw = (tv[k] > tv[k - 1]) || (tv[k] == tv[k - 1] && tj[k] < tj[k - 1]);
    if (sw) {
      float fv = tv[k]; tv[k] = tv[k - 1]; tv[k - 1] = fv;
      int ti = tj[k]; tj[k] = tj[k - 1]; tj[k - 1] = ti;
    }
  }
}

// ---------------- per-row top-4 within a 128-col j-chunk (bf16 MFMA) ----------------
// Ranking: v = relu(dot * rnj) -- same order & zero-ties as relu(dot/(ni*nj)).
// TKNJC=8 chunks: no atomics here, so occupancy is the binding constraint.
__global__ __launch_bounds__(256) void topk_part_kernel(
    const float* __restrict__ x, const float* __restrict__ rn,
    float* __restrict__ candV, int* __restrict__ candI) {
  __shared__ __align__(16) float cV[64][65];     // overlaid: Xj tile during j-loop
  __shared__ unsigned short cI[64][66];
  bf (*Xj)[LDK] = (bf(*)[LDK])cV;                // 9216 B <= 16640 B, safe overlay
  const int b = blockIdx.z, h = blockIdx.y;
  const int it = blockIdx.x >> 3, jc = blockIdx.x & 7;
  const int i0 = it * 64;
  const int tid = threadIdx.x, lane = tid & 63, w = tid >> 6;
  const int m = lane & 15, quad = lane >> 4;

  short8 afrag[2];
  load_afrag(&x[((size_t)b * NUM + i0 + w * 16 + m) * CH + h * DK], quad, afrag);

  float tv[4][4]; int tj[4][4];
  #pragma unroll
  for (int r = 0; r < 4; ++r)
    #pragma unroll
    for (int q = 0; q < 4; ++q) { tv[r][q] = -1.f; tj[r][q] = 0xffff; }

  for (int jt = 0; jt < 2; ++jt) {
    int j0 = jc * 128 + jt * 64;
    __syncthreads();
    stage_tile(x, (size_t)b * NUM + j0, h * DK, CH, Xj, tid);
    __syncthreads();
    #pragma unroll
    for (int nt = 0; nt < 4; ++nt) {
      f32x4 acc = {0.f, 0.f, 0.f, 0.f};
      #pragma unroll
      for (int kb = 0; kb < 2; ++kb) {
        short8 bb = *(const short8*)&Xj[nt * 16 + m][kb * 32 + quad * 8];
        acc = __builtin_amdgcn_mfma_f32_16x16x32_bf16(afrag[kb], bb, acc, 0, 0, 0);
      }
      int j = j0 + nt * 16 + m;
      float rnj = rn[((size_t)b * NUM + j) * HEADS + h];
      #pragma unroll
      for (int r = 0; r < 4; ++r) {
        float v = fmaxf(acc[r] * rnj, 0.f);
        ins4(v, j, tv[r], tj[r]);
      }
    }
  }
  __syncthreads();  // Xj dead; reuse memory as cV/cI
  #pragma unroll
  for (int r = 0; r < 4; ++r)
    #pragma unroll
    for (int q = 0; q < 4; ++q) {
      cV[w * 16 + quad * 4 + r][m * 4 + q] = tv[r][q];
      cI[w * 16 + quad * 4 + r][m * 4 + q] = (unsigned short)tj[r][q];
    }
  __syncthreads();
  if (tid < 64) {
    float fv[4] = {-1.f, -1.f, -1.f, -1.f};
    int fi[4] = {0x7fffffff, 0x7fffffff, 0x7fffffff, 0x7fffffff};
    for (int q = 0; q < 64; ++q) ins4(cV[tid][q], (int)cI[tid][q], fv, fi);
    size_t base = (size_t)((((b * HEADS + h) * 16 + it) * TKNJC + jc) * 64 + tid) * 4;
    #pragma unroll
    for (int q = 0; q < 4; ++q) { candV[base + q] = fv[q]; candI[base + q] = fi[q]; }
  }
}

// ---------------- merge TKNJC chunk candidates per row -> union into vec ----------------
__global__ __launch_bounds__(256) void topk_merge_kernel(
    const float* __restrict__ candV, const int* __restrict__ candI,
    float* __restrict__ vec) {
  int t = blockIdx.x * 256 + threadIdx.x;   // t = bhit*64 + rl
  int bhit = t >> 6, rl = t & 63;
  float fv[4] = {-1.f, -1.f, -1.f, -1.f};
  int fi[4] = {0x7fffffff, 0x7fffffff, 0x7fffffff, 0x7fffffff};
  #pragma unroll
  for (int jc = 0; jc < TKNJC; ++jc) {
    size_t base = (size_t)(((bhit) * TKNJC + jc) * 64 + rl) * 4;
    #pragma unroll
    for (int q = 0; q < 4; ++q) ins4(candV[base + q], candI[base + q], fv, fi);
  }
  #pragma unroll
  for (int q = 0; q < 4; ++q) vec[fi[q]] = 1.0f;  // benign race, all write 1
}

// ---------------- masked attention apply (bf16 MFMA scores + PV), j-chunked ----------------
// Ws[i][j] = pkbit(i,j) * relu(cos_ij)*0.25 ; PV uses vec-masked conv^T tile.
// Diagonal f_mask term is pre-seeded into `out` by conv. NJC=4: atomics bind.
__global__ __launch_bounds__(256) void apply_kernel(
    const float* __restrict__ x, const float* __restrict__ conv,
    float* __restrict__ out, const float* __restrict__ rn,
    const float* __restrict__ vec, const u64* __restrict__ pk) {
  __shared__ __align__(16) bf Xj[64][LDK];
  __shared__ __align__(16) bf Cv[64][LDK];
  __shared__ __align__(16) bf Ws[64][LDK];
  const int b = blockIdx.z, h = blockIdx.y;
  const int it = blockIdx.x >> 2, jc = blockIdx.x & 3;
  const int i0 = it * 64;
  const int tid = threadIdx.x, lane = tid & 63, w = tid >> 6;
  const int m = lane & 15, quad = lane >> 4;

  short8 afrag[2];
  load_afrag(&x[((size_t)b * NUM + i0 + w * 16 + m) * CH + h * DK], quad, afrag);

  float rni4[4];
  #pragma unroll
  for (int r = 0; r < 4; ++r) {
    int row = i0 + w * 16 + quad * 4 + r;
    rni4[r] = 0.25f * rn[((size_t)b * NUM + row) * HEADS + h];
  }
  f32x4 om[4] = {{0.f,0.f,0.f,0.f},{0.f,0.f,0.f,0.f},{0.f,0.f,0.f,0.f},{0.f,0.f,0.f,0.f}};

  for (int jt = 0; jt < 4; ++jt) {
    int j0 = jc * 256 + jt * 64;
    __syncthreads();   // protect Xj/Cv from previous iteration's readers
    stage_tile(x, (size_t)b * NUM + j0, h * DK, CH, Xj, tid);
    {  // vec-masked conv^T tile
      int jr = tid >> 4, c4 = tid & 15;
      #pragma unroll
      for (int itt = 0; itt < 4; ++itt) {
        int j = jr + itt * 16;
        float vm = vec[j0 + j];
        const float4 v = *(const float4*)&conv[((size_t)b * NUM + j0 + j) * CH + h * DK + c4 * 4];
        Cv[c4 * 4 + 0][j] = tobf(v.x * vm);
        Cv[c4 * 4 + 1][j] = tobf(v.y * vm);
        Cv[c4 * 4 + 2][j] = tobf(v.z * vm);
        Cv[c4 * 4 + 3][j] = tobf(v.w * vm);
      }
    }
    u64 wr[4];
    #pragma unroll
    for (int r = 0; r < 4; ++r)
      wr[r] = pk[((size_t)b * NUM + i0 + w * 16 + quad * 4 + r) * 16 + (j0 >> 6)];
    __syncthreads();
    // scores -> masked weights -> Ws (own wave's 16-row stripe only)
    #pragma unroll
    for (int nt = 0; nt < 4; ++nt) {
      f32x4 acc = {0.f, 0.f, 0.f, 0.f};
      #pragma unroll
      for (int kb = 0; kb < 2; ++kb) {
        short8 bb = *(const short8*)&Xj[nt * 16 + m][kb * 32 + quad * 8];
        acc = __builtin_amdgcn_mfma_f32_16x16x32_bf16(afrag[kb], bb, acc, 0, 0, 0);
      }
      float rnj = rn[((size_t)b * NUM + j0 + nt * 16 + m) * HEADS + h];
      #pragma unroll
      for (int r = 0; r < 4; ++r) {
        float a = fmaxf(acc[r] * rni4[r] * rnj, 0.f);
        bool bit = (wr[r] >> (nt * 16 + m)) & 1ull;
        Ws[w * 16 + quad * 4 + r][nt * 16 + m] = tobf(bit ? a : 0.f);
      }
    }
    // PV: same-wave Ws stripe + Cv (stable until next loop-top barrier)
    #pragma unroll
    for (int kb = 0; kb < 2; ++kb) {
      short8 a = *(const short8*)&Ws[w * 16 + m][kb * 32 + quad * 8];
      #pragma unroll
      for (int ct = 0; ct < 4; ++ct) {
        short8 bb = *(const short8*)&Cv[ct * 16 + m][kb * 32 + quad * 8];
        om[ct] = __builtin_amdgcn_mfma_f32_16x16x32_bf16(a, bb, om[ct], 0, 0, 0);
      }
    }
  }
  #pragma unroll
  for (int ct = 0; ct < 4; ++ct)
    #pragma unroll
    for (int r = 0; r < 4; ++r) {
      size_t idx = ((size_t)b * NUM + i0 + w * 16 + quad * 4 + r) * CH + h * DK + ct * 16 + m;
      atomicAdd(&out[idx], om[ct][r]);
    }
}

// ---------------- LayerNorm + final outputs (in-place on d_out regions) ----------------
__global__ __launch_bounds__(256) void final_kernel(
    float* __restrict__ ybnf, float* __restrict__ out0,
    const float* __restrict__ lnw, const float* __restrict__ lnb) {
  __shared__ float r1[4];
  __shared__ float r2[4];
  int bn = blockIdx.x;
  int c = threadIdx.x;
  size_t idx = (size_t)bn * CH + c;
  float y = ybnf[idx];
  float x2v = out0[idx];
  float s = y;
  #pragma unroll
  for (int off = 32; off; off >>= 1) s += __shfl_down(s, off, 64);
  int wave = c >> 6, lane = c & 63;
  if (lane == 0) r1[wave] = s;
  __syncthreads();
  float mu = (r1[0] + r1[1] + r1[2] + r1[3]) * (1.f / 256.f);
  float d = y - mu;
  float s2 = d * d;
  #pragma unroll
  for (int off = 32; off; off >>= 1) s2 += __shfl_down(s2, off, 64);
  if (lane == 0) r2[wave] = s2;
  __syncthreads();
  float var = (r2[0] + r2[1] + r2[2] + r2[3]) * (1.f / 256.f);
  float nf = d * rsqrtf(var + 1e-6f) * lnw[c] + lnb[c];
  ybnf[idx] = nf;
  out0[idx] = x2v + nf;
}

extern "C" void kernel_launch(void* const* d_in, const int* in_sizes, int n_in,
                              void* d_out, int out_size, void* d_ws, size_t ws_size,
                              hipStream_t stream) {
  const float* input = (const float*)d_in[0];
  const int* mroi = (const int*)d_in[1];
  const int* smask = (const int*)d_in[2];
  const float* gt_feat = (const float*)d_in[3];
  const float* w1 = (const float*)d_in[4];
  const float* b1 = (const float*)d_in[5];
  const float* w2 = (const float*)d_in[6];
  const float* b2 = (const float*)d_in[7];
  const float* gt_w = (const float*)d_in[8];
  const float* gt_b = (const float*)d_in[9];
  const float* lnw = (const float*)d_in[10];
  const float* lnb = (const float*)d_in[11];

  const size_t SEG = (size_t)B_ * NUM * CH;  // 1048576 elements
  float* out0 = (float*)d_out;     // finally: out2^T + node_feat ; interim: X2 (conv2)
  float* gts = out0 + SEG;         // gts output (final from the start)
  float* nfreg = out0 + 2 * SEG;   // finally: node_feat ; interim: X1 then Yb

  // ws: F1 4MB | RN 64KB | VEC 8KB | candV 2MB | candI 2MB | PK 512KB ~= 8.6 MB
  float* F1 = (float*)d_ws;
  float* RN = F1 + SEG;
  float* VEC1 = RN + (size_t)B_ * NUM * HEADS;
  float* VEC2 = VEC1 + NUM;
  float* candV = VEC2 + NUM;
  const size_t NCAND = (size_t)B_ * HEADS * 16 * TKNJC * 64 * 4;
  int* candI = (int*)(candV + NCAND);
  u64* PK = (u64*)(candI + NCAND);

  float* X1 = nfreg;  // conv1 output (F1 seeded = X1*(1+0.25*[sm==0]))
  float* X2 = out0;   // conv2 output lives in out0 region until final_kernel
  float* Yb = nfreg;  // o2m accumulator (seeded = 0.25*[sm==0]*X2, overwrites dead X1)

  // fused: conv1 (y<4) + gts (y 4..7) + pack/vec-zero (y 8..23)
  head_kernel<<<dim3(64, 24), 256, 0, stream>>>(
      input, w1, b1, smask, X1, F1, RN,
      gt_feat, gt_w, gt_b, gts, mroi, PK, VEC1, VEC2);

  // stage 1
  topk_part_kernel<<<dim3(16 * TKNJC, HEADS, B_), 256, 0, stream>>>(input, RN, candV, candI);
  topk_merge_kernel<<<64, 256, 0, stream>>>(candV, candI, VEC1);
  apply_kernel<<<dim3(16 * NJC, HEADS, B_), 256, 0, stream>>>(
      input, X1, F1, RN, VEC1, PK);

  // stage 2
  conv_kernel<<<dim3(64, 4), 256, 0, stream>>>(F1, w2, b2, smask, 0.0f, X2, Yb, RN);
  topk_part_kernel<<<dim3(16 * TKNJC, HEADS, B_), 256, 0, stream>>>(F1, RN, candV, candI);
  topk_merge_kernel<<<64, 256, 0, stream>>>(candV, candI, VEC2);
  apply_kernel<<<dim3(16 * NJC, HEADS, B_), 256, 0, stream>>>(
      F1, X2, Yb, RN, VEC2, PK);

  final_kernel<<<4096, 256, 0, stream>>>(Yb, X2, lnw, lnb);
}

// Round 14
// 272.031 us; speedup vs baseline: 1.0622x; 1.0622x over previous
//
#include <hip/hip_runtime.h>
#include <hip/hip_bf16.h>

#define B_    4
#define NUM   1024
#define CH    256
#define HEADS 4
#define DK    64
#define LDK   72   // padded LDS row stride in bf16 elements (2-way bank alias = free)
#define NJC   4    // j-chunks per (b,h,i-tile); chunk = 256 cols = 4 j-tiles

typedef __hip_bfloat16 bf;
typedef __attribute__((ext_vector_type(8))) short short8;
typedef __attribute__((ext_vector_type(4))) float f32x4;
typedef unsigned long long u64;

__device__ inline bf tobf(float v) { return __float2bfloat16(v); }

// stage a 64x64 fp32 global tile -> bf16 LDS tile [64][LDK]
__device__ inline void stage_tile(const float* __restrict__ src, size_t row0,
                                  int col0, int rowstride, bf (*dst)[LDK], int tid) {
  int r = tid >> 4, c4 = (tid & 15) * 4;
  #pragma unroll
  for (int it = 0; it < 4; ++it) {
    int row = r + it * 16;
    const float4 v = *(const float4*)&src[(row0 + row) * (size_t)rowstride + col0 + c4];
    union { bf h4[4]; short4 s4; } u;
    u.h4[0] = tobf(v.x); u.h4[1] = tobf(v.y); u.h4[2] = tobf(v.z); u.h4[3] = tobf(v.w);
    *(short4*)&dst[row][c4] = u.s4;
  }
}

// load this lane's A-fragments (2 k-blocks) straight from global into registers
__device__ inline void load_afrag(const float* __restrict__ arow, int quad, short8 af[2]) {
  #pragma unroll
  for (int kb = 0; kb < 2; ++kb) {
    const float4 v0 = *(const float4*)&arow[kb * 32 + quad * 8];
    const float4 v1 = *(const float4*)&arow[kb * 32 + quad * 8 + 4];
    union { bf hh[8]; short8 s; } u;
    u.hh[0] = tobf(v0.x); u.hh[1] = tobf(v0.y); u.hh[2] = tobf(v0.z); u.hh[3] = tobf(v0.w);
    u.hh[4] = tobf(v1.x); u.hh[5] = tobf(v1.y); u.hh[6] = tobf(v1.z); u.hh[7] = tobf(v1.w);
    af[kb] = u.s;
  }
}

// ---------------- conv body: grouped 1x1 conv + relu, dual write + rn ----------------
__device__ inline void conv_body(
    char* SM, int m0, int g, int tid,
    const float* __restrict__ x, const float* __restrict__ w,
    const float* __restrict__ bias, const int* __restrict__ smask,
    float seedbase, float* __restrict__ out, float* __restrict__ out2,
    float* __restrict__ rn) {
  float (*Xs)[65] = (float(*)[65])SM;
  float (*Wsm)[65] = (float(*)[65])(SM + 16640);
  const int tx = tid & 15, ty = tid >> 4;
  #pragma unroll
  for (int l = 0; l < 16; ++l) {
    int idx = tid + l * 256; int r = idx >> 6, c = idx & 63;
    Xs[r][c] = x[(size_t)(m0 + r) * CH + g * DK + c];
    Wsm[r][c] = w[g * DK * DK + r * DK + c];
  }
  __syncthreads();
  {  // fused reciprocal norms: 4 lanes per row, 16 channels each
    int wv = tid >> 6, lane = tid & 63;
    int row = wv * 16 + (lane >> 2), part = lane & 3;
    float s = 0.f;
    #pragma unroll
    for (int k = 0; k < 16; ++k) {
      float v = Xs[row][part * 16 + k];
      s += v * v;
    }
    s += __shfl_xor(s, 1, 64);
    s += __shfl_xor(s, 2, 64);
    if (part == 0)
      rn[(size_t)(m0 + row) * HEADS + g] = 1.0f / fmaxf(sqrtf(s), 1e-4f);
  }
  float acc[4][4] = {};
  #pragma unroll 8
  for (int k = 0; k < DK; ++k) {
    float av[4], bv[4];
    #pragma unroll
    for (int i = 0; i < 4; ++i) av[i] = Xs[ty * 4 + i][k];
    #pragma unroll
    for (int j = 0; j < 4; ++j) bv[j] = Wsm[tx * 4 + j][k];
    #pragma unroll
    for (int i = 0; i < 4; ++i)
      #pragma unroll
      for (int j = 0; j < 4; ++j) acc[i][j] += av[i] * bv[j];
  }
  #pragma unroll
  for (int i = 0; i < 4; ++i) {
    int row = m0 + ty * 4 + i;
    float seed = seedbase + ((smask[row] == 0) ? 0.25f : 0.f);
    #pragma unroll
    for (int j = 0; j < 4; ++j) {
      int o = g * DK + tx * 4 + j;
      size_t idx = (size_t)row * CH + o;
      float v = fmaxf(acc[i][j] + bias[o], 0.f);
      out[idx] = v;
      out2[idx] = v * seed;
    }
  }
}

// ---------------- gts body: relu(gt_feat @ gt_w^T + gt_b), bf16 MFMA ----------------
__device__ inline void gts_body(
    char* SM, int m0, int n0, int tid,
    const float* __restrict__ gf, const float* __restrict__ gw,
    const float* __restrict__ gb, float* __restrict__ out) {
  bf (*As)[LDK] = (bf(*)[LDK])SM;
  bf (*Bs)[LDK] = (bf(*)[LDK])(SM + 9216);
  const int lane = tid & 63, w = tid >> 6;
  const int m = lane & 15, quad = lane >> 4;
  f32x4 acc[4] = {{0.f,0.f,0.f,0.f},{0.f,0.f,0.f,0.f},{0.f,0.f,0.f,0.f},{0.f,0.f,0.f,0.f}};
  for (int k0 = 0; k0 < 256; k0 += 64) {
    __syncthreads();
    stage_tile(gf, m0, k0, 256, As, tid);
    stage_tile(gw, n0, k0, 256, Bs, tid);
    __syncthreads();
    #pragma unroll
    for (int kb = 0; kb < 2; ++kb) {
      short8 a = *(const short8*)&As[w * 16 + m][kb * 32 + quad * 8];
      #pragma unroll
      for (int nt = 0; nt < 4; ++nt) {
        short8 bb = *(const short8*)&Bs[nt * 16 + m][kb * 32 + quad * 8];
        acc[nt] = __builtin_amdgcn_mfma_f32_16x16x32_bf16(a, bb, acc[nt], 0, 0, 0);
      }
    }
  }
  #pragma unroll
  for (int nt = 0; nt < 4; ++nt)
    #pragma unroll
    for (int r = 0; r < 4; ++r) {
      int row = m0 + w * 16 + quad * 4 + r, col = n0 + nt * 16 + m;
      out[(size_t)row * 256 + col] = fmaxf(acc[nt][r] + gb[col], 0.f);
    }
}

// ================ mega head kernel: conv1 (y<4) | gts (y 4..7) | pack (y 8..23) ================
__global__ __launch_bounds__(256) void head_kernel(
    const float* __restrict__ x, const float* __restrict__ w1,
    const float* __restrict__ b1, const int* __restrict__ smask,
    float* __restrict__ X1, float* __restrict__ F1, float* __restrict__ rn,
    const float* __restrict__ gf, const float* __restrict__ gw,
    const float* __restrict__ gb, float* __restrict__ gts_out,
    const int* __restrict__ mroi, u64* __restrict__ pk,
    float* __restrict__ v1, float* __restrict__ v2) {
  __shared__ __align__(16) char SM[33280];
  const int tid = threadIdx.x;
  if (blockIdx.y < 4) {
    conv_body(SM, blockIdx.x * 64, blockIdx.y, tid, x, w1, b1, smask, 1.0f, X1, F1, rn);
  } else if (blockIdx.y < 8) {
    gts_body(SM, blockIdx.x * 64, (blockIdx.y - 4) * 64, tid, gf, gw, gb, gts_out);
  } else {
    int blkrow = (blockIdx.y - 8) * 64 + blockIdx.x;   // 0..1023
    if (blkrow < 4) {
      int i = blkrow * 256 + tid;
      v1[i] = 0.f; v2[i] = 0.f;
    }
    int row = blkrow * 4 + (tid >> 6);
    int lane = tid & 63;
    int b = row >> 10;
    const int* mr = &mroi[(size_t)row * NUM];
    const int* sm = &smask[b * NUM];
    #pragma unroll
    for (int wd = 0; wd < 16; ++wd) {
      int j = wd * 64 + lane;
      u64 word = __ballot((mr[j] != 0) && (sm[j] != 0));
      if (lane == 0) pk[(size_t)row * 16 + wd] = word;
    }
  }
}

// ---------------- grouped 1x1 conv + relu (fp32) standalone (stage 2) ----------------
__global__ __launch_bounds__(256) void conv_kernel(
    const float* __restrict__ x, const float* __restrict__ w,
    const float* __restrict__ bias, const int* __restrict__ smask,
    float seedbase, float* __restrict__ out, float* __restrict__ out2,
    float* __restrict__ rn) {
  __shared__ __align__(16) char SM[33280];
  conv_body(SM, blockIdx.x * 64, blockIdx.y, threadIdx.x, x, w, bias, smask,
            seedbase, out, out2, rn);
}

// top-4 insert, jax-stable tie-break (higher value first; equal value -> lower index)
__device__ inline void ins4(float v, int id, float tv[4], int tj[4]) {
  if (v < tv[3] || (v == tv[3] && id > tj[3])) return;
  tv[3] = v; tj[3] = id;
  #pragma unroll
  for (int k = 3; k > 0; --k) {
    bool sw = (tv[k] > tv[k - 1]) || (tv[k] == tv[k - 1] && tj[k] < tj[k - 1]);
    if (sw) {
      float fv = tv[k]; tv[k] = tv[k - 1]; tv[k - 1] = fv;
      int ti = tj[k]; tj[k] = tj[k - 1]; tj[k - 1] = ti;
    }
  }
}

// ---------------- per-row top-4 within a 256-col j-chunk (bf16 MFMA) ----------------
// Ranking: v = relu(dot * rnj) -- same order & zero-ties as relu(dot/(ni*nj)).
__global__ __launch_bounds__(256) void topk_part_kernel(
    const float* __restrict__ x, const float* __restrict__ rn,
    float* __restrict__ candV, int* __restrict__ candI) {
  __shared__ __align__(16) float cV[64][65];     // overlaid: Xj tile during j-loop
  __shared__ unsigned short cI[64][66];
  bf (*Xj)[LDK] = (bf(*)[LDK])cV;                // 9216 B <= 16640 B, safe overlay
  const int b = blockIdx.z, h = blockIdx.y;
  const int it = blockIdx.x >> 2, jc = blockIdx.x & 3;
  const int i0 = it * 64;
  const int tid = threadIdx.x, lane = tid & 63, w = tid >> 6;
  const int m = lane & 15, quad = lane >> 4;

  short8 afrag[2];
  load_afrag(&x[((size_t)b * NUM + i0 + w * 16 + m) * CH + h * DK], quad, afrag);

  float tv[4][4]; int tj[4][4];
  #pragma unroll
  for (int r = 0; r < 4; ++r)
    #pragma unroll
    for (int q = 0; q < 4; ++q) { tv[r][q] = -1.f; tj[r][q] = 0xffff; }

  for (int jt = 0; jt < 4; ++jt) {
    int j0 = jc * 256 + jt * 64;
    __syncthreads();
    stage_tile(x, (size_t)b * NUM + j0, h * DK, CH, Xj, tid);
    __syncthreads();
    #pragma unroll
    for (int nt = 0; nt < 4; ++nt) {
      f32x4 acc = {0.f, 0.f, 0.f, 0.f};
      #pragma unroll
      for (int kb = 0; kb < 2; ++kb) {
        short8 bb = *(const short8*)&Xj[nt * 16 + m][kb * 32 + quad * 8];
        acc = __builtin_amdgcn_mfma_f32_16x16x32_bf16(afrag[kb], bb, acc, 0, 0, 0);
      }
      int j = j0 + nt * 16 + m;
      float rnj = rn[((size_t)b * NUM + j) * HEADS + h];
      #pragma unroll
      for (int r = 0; r < 4; ++r) {
        float v = fmaxf(acc[r] * rnj, 0.f);
        ins4(v, j, tv[r], tj[r]);
      }
    }
  }
  __syncthreads();  // Xj dead; reuse memory as cV/cI
  #pragma unroll
  for (int r = 0; r < 4; ++r)
    #pragma unroll
    for (int q = 0; q < 4; ++q) {
      cV[w * 16 + quad * 4 + r][m * 4 + q] = tv[r][q];
      cI[w * 16 + quad * 4 + r][m * 4 + q] = (unsigned short)tj[r][q];
    }
  __syncthreads();
  if (tid < 64) {
    float fv[4] = {-1.f, -1.f, -1.f, -1.f};
    int fi[4] = {0x7fffffff, 0x7fffffff, 0x7fffffff, 0x7fffffff};
    for (int q = 0; q < 64; ++q) ins4(cV[tid][q], (int)cI[tid][q], fv, fi);
    size_t base = (size_t)((((b * HEADS + h) * 16 + it) * NJC + jc) * 64 + tid) * 4;
    #pragma unroll
    for (int q = 0; q < 4; ++q) { candV[base + q] = fv[q]; candI[base + q] = fi[q]; }
  }
}

// ---------------- merge NJC chunk candidates per row -> union into vec ----------------
__global__ __launch_bounds__(256) void topk_merge_kernel(
    const float* __restrict__ candV, const int* __restrict__ candI,
    float* __restrict__ vec) {
  int t = blockIdx.x * 256 + threadIdx.x;   // t = bhit*64 + rl
  int bhit = t >> 6, rl = t & 63;
  float fv[4] = {-1.f, -1.f, -1.f, -1.f};
  int fi[4] = {0x7fffffff, 0x7fffffff, 0x7fffffff, 0x7fffffff};
  #pragma unroll
  for (int jc = 0; jc < NJC; ++jc) {
    size_t base = (size_t)(((bhit) * NJC + jc) * 64 + rl) * 4;
    #pragma unroll
    for (int q = 0; q < 4; ++q) ins4(candV[base + q], candI[base + q], fv, fi);
  }
  #pragma unroll
  for (int q = 0; q < 4; ++q) vec[fi[q]] = 1.0f;  // benign race, all write 1
}

// ---------------- masked attention apply (bf16 MFMA scores + PV), j-chunked ----------------
// Ws[i][j] = pkbit(i,j) * relu(cos_ij)*0.25 ; PV uses vec-masked conv^T tile.
// Diagonal f_mask term is pre-seeded into `out` by conv. NJC=4: atomics bind.
__global__ __launch_bounds__(256) void apply_kernel(
    const float* __restrict__ x, const float* __restrict__ conv,
    float* __restrict__ out, const float* __restrict__ rn,
    const float* __restrict__ vec, const u64* __restrict__ pk) {
  __shared__ __align__(16) bf Xj[64][LDK];
  __shared__ __align__(16) bf Cv[64][LDK];
  __shared__ __align__(16) bf Ws[64][LDK];
  const int b = blockIdx.z, h = blockIdx.y;
  const int it = blockIdx.x >> 2, jc = blockIdx.x & 3;
  const int i0 = it * 64;
  const int tid = threadIdx.x, lane = tid & 63, w = tid >> 6;
  const int m = lane & 15, quad = lane >> 4;

  short8 afrag[2];
  load_afrag(&x[((size_t)b * NUM + i0 + w * 16 + m) * CH + h * DK], quad, afrag);

  float rni4[4];
  #pragma unroll
  for (int r = 0; r < 4; ++r) {
    int row = i0 + w * 16 + quad * 4 + r;
    rni4[r] = 0.25f * rn[((size_t)b * NUM + row) * HEADS + h];
  }
  f32x4 om[4] = {{0.f,0.f,0.f,0.f},{0.f,0.f,0.f,0.f},{0.f,0.f,0.f,0.f},{0.f,0.f,0.f,0.f}};

  for (int jt = 0; jt < 4; ++jt) {
    int j0 = jc * 256 + jt * 64;
    __syncthreads();   // protect Xj/Cv from previous iteration's readers
    stage_tile(x, (size_t)b * NUM + j0, h * DK, CH, Xj, tid);
    {  // vec-masked conv^T tile
      int jr = tid >> 4, c4 = tid & 15;
      #pragma unroll
      for (int itt = 0; itt < 4; ++itt) {
        int j = jr + itt * 16;
        float vm = vec[j0 + j];
        const float4 v = *(const float4*)&conv[((size_t)b * NUM + j0 + j) * CH + h * DK + c4 * 4];
        Cv[c4 * 4 + 0][j] = tobf(v.x * vm);
        Cv[c4 * 4 + 1][j] = tobf(v.y * vm);
        Cv[c4 * 4 + 2][j] = tobf(v.z * vm);
        Cv[c4 * 4 + 3][j] = tobf(v.w * vm);
      }
    }
    u64 wr[4];
    #pragma unroll
    for (int r = 0; r < 4; ++r)
      wr[r] = pk[((size_t)b * NUM + i0 + w * 16 + quad * 4 + r) * 16 + (j0 >> 6)];
    __syncthreads();
    // scores -> masked weights -> Ws (own wave's 16-row stripe only)
    #pragma unroll
    for (int nt = 0; nt < 4; ++nt) {
      f32x4 acc = {0.f, 0.f, 0.f, 0.f};
      #pragma unroll
      for (int kb = 0; kb < 2; ++kb) {
        short8 bb = *(const short8*)&Xj[nt * 16 + m][kb * 32 + quad * 8];
        acc = __builtin_amdgcn_mfma_f32_16x16x32_bf16(afrag[kb], bb, acc, 0, 0, 0);
      }
      float rnj = rn[((size_t)b * NUM + j0 + nt * 16 + m) * HEADS + h];
      #pragma unroll
      for (int r = 0; r < 4; ++r) {
        float a = fmaxf(acc[r] * rni4[r] * rnj, 0.f);
        bool bit = (wr[r] >> (nt * 16 + m)) & 1ull;
        Ws[w * 16 + quad * 4 + r][nt * 16 + m] = tobf(bit ? a : 0.f);
      }
    }
    // PV: same-wave Ws stripe + Cv (stable until next loop-top barrier)
    #pragma unroll
    for (int kb = 0; kb < 2; ++kb) {
      short8 a = *(const short8*)&Ws[w * 16 + m][kb * 32 + quad * 8];
      #pragma unroll
      for (int ct = 0; ct < 4; ++ct) {
        short8 bb = *(const short8*)&Cv[ct * 16 + m][kb * 32 + quad * 8];
        om[ct] = __builtin_amdgcn_mfma_f32_16x16x32_bf16(a, bb, om[ct], 0, 0, 0);
      }
    }
  }
  #pragma unroll
  for (int ct = 0; ct < 4; ++ct)
    #pragma unroll
    for (int r = 0; r < 4; ++r) {
      size_t idx = ((size_t)b * NUM + i0 + w * 16 + quad * 4 + r) * CH + h * DK + ct * 16 + m;
      atomicAdd(&out[idx], om[ct][r]);
    }
}

// ---------------- LayerNorm + final outputs (in-place on d_out regions) ----------------
__global__ __launch_bounds__(256) void final_kernel(
    float* __restrict__ ybnf, float* __restrict__ out0,
    const float* __restrict__ lnw, const float* __restrict__ lnb) {
  __shared__ float r1[4];
  __shared__ float r2[4];
  int bn = blockIdx.x;
  int c = threadIdx.x;
  size_t idx = (size_t)bn * CH + c;
  float y = ybnf[idx];
  float x2v = out0[idx];
  float s = y;
  #pragma unroll
  for (int off = 32; off; off >>= 1) s += __shfl_down(s, off, 64);
  int wave = c >> 6, lane = c & 63;
  if (lane == 0) r1[wave] = s;
  __syncthreads();
  float mu = (r1[0] + r1[1] + r1[2] + r1[3]) * (1.f / 256.f);
  float d = y - mu;
  float s2 = d * d;
  #pragma unroll
  for (int off = 32; off; off >>= 1) s2 += __shfl_down(s2, off, 64);
  if (lane == 0) r2[wave] = s2;
  __syncthreads();
  float var = (r2[0] + r2[1] + r2[2] + r2[3]) * (1.f / 256.f);
  float nf = d * rsqrtf(var + 1e-6f) * lnw[c] + lnb[c];
  ybnf[idx] = nf;
  out0[idx] = x2v + nf;
}

extern "C" void kernel_launch(void* const* d_in, const int* in_sizes, int n_in,
                              void* d_out, int out_size, void* d_ws, size_t ws_size,
                              hipStream_t stream) {
  const float* input = (const float*)d_in[0];
  const int* mroi = (const int*)d_in[1];
  const int* smask = (const int*)d_in[2];
  const float* gt_feat = (const float*)d_in[3];
  const float* w1 = (const float*)d_in[4];
  const float* b1 = (const float*)d_in[5];
  const float* w2 = (const float*)d_in[6];
  const float* b2 = (const float*)d_in[7];
  const float* gt_w = (const float*)d_in[8];
  const float* gt_b = (const float*)d_in[9];
  const float* lnw = (const float*)d_in[10];
  const float* lnb = (const float*)d_in[11];

  const size_t SEG = (size_t)B_ * NUM * CH;  // 1048576 elements
  float* out0 = (float*)d_out;     // finally: out2^T + node_feat ; interim: X2 (conv2)
  float* gts = out0 + SEG;         // gts output (final from the start)
  float* nfreg = out0 + 2 * SEG;   // finally: node_feat ; interim: X1 then Yb

  // ws: F1 4MB | RN 64KB | VEC 8KB | candV 1MB | candI 1MB | PK 512KB ~= 6.6 MB
  float* F1 = (float*)d_ws;
  float* RN = F1 + SEG;
  float* VEC1 = RN + (size_t)B_ * NUM * HEADS;
  float* VEC2 = VEC1 + NUM;
  float* candV = VEC2 + NUM;
  const size_t NCAND = (size_t)B_ * HEADS * 16 * NJC * 64 * 4;
  int* candI = (int*)(candV + NCAND);
  u64* PK = (u64*)(candI + NCAND);

  float* X1 = nfreg;  // conv1 output (F1 seeded = X1*(1+0.25*[sm==0]))
  float* X2 = out0;   // conv2 output lives in out0 region until final_kernel
  float* Yb = nfreg;  // o2m accumulator (seeded = 0.25*[sm==0]*X2, overwrites dead X1)

  // fused: conv1 (y<4) + gts (y 4..7) + pack/vec-zero (y 8..23)
  head_kernel<<<dim3(64, 24), 256, 0, stream>>>(
      input, w1, b1, smask, X1, F1, RN,
      gt_feat, gt_w, gt_b, gts, mroi, PK, VEC1, VEC2);

  // stage 1
  topk_part_kernel<<<dim3(16 * NJC, HEADS, B_), 256, 0, stream>>>(input, RN, candV, candI);
  topk_merge_kernel<<<64, 256, 0, stream>>>(candV, candI, VEC1);
  apply_kernel<<<dim3(16 * NJC, HEADS, B_), 256, 0, stream>>>(
      input, X1, F1, RN, VEC1, PK);

  // stage 2
  conv_kernel<<<dim3(64, 4), 256, 0, stream>>>(F1, w2, b2, smask, 0.0f, X2, Yb, RN);
  topk_part_kernel<<<dim3(16 * NJC, HEADS, B_), 256, 0, stream>>>(F1, RN, candV, candI);
  topk_merge_kernel<<<64, 256, 0, stream>>>(candV, candI, VEC2);
  apply_kernel<<<dim3(16 * NJC, HEADS, B_), 256, 0, stream>>>(
      F1, X2, Yb, RN, VEC2, PK);

  final_kernel<<<4096, 256, 0, stream>>>(Yb, X2, lnw, lnb);
}

// Round 15
// 264.143 us; speedup vs baseline: 1.0939x; 1.0299x over previous
//
#include <hip/hip_runtime.h>
#include <hip/hip_bf16.h>

#define B_    4
#define NUM   1024
#define CH    256
#define HEADS 4
#define DK    64
#define LDK   72   // padded LDS row stride in bf16 elements (2-way bank alias = free)
#define NJC   4    // j-chunks per (b,h,i-tile); chunk = 256 cols = 4 j-tiles

typedef __hip_bfloat16 bf;
typedef __attribute__((ext_vector_type(8))) short short8;
typedef __attribute__((ext_vector_type(4))) float f32x4;
typedef unsigned long long u64;

__device__ inline bf tobf(float v) { return __float2bfloat16(v); }

// stage a 64x64 bf16 global tile -> bf16 LDS tile [64][LDK] (raw short8 copies)
__device__ inline void stage_tile_bf(const bf* __restrict__ src, size_t row0,
                                     int col0, int rowstride, bf (*dst)[LDK], int tid) {
  int row = tid >> 3, chunk = tid & 7;   // 32 rows per pass, 8 chunks of 8 elems
  #pragma unroll
  for (int it = 0; it < 2; ++it) {
    int r = row + it * 32;
    *(short8*)&dst[r][chunk * 8] =
        *(const short8*)&src[(row0 + r) * (size_t)rowstride + col0 + chunk * 8];
  }
}

// stage a 64x64 fp32 global tile -> bf16 LDS tile (convert path, gts only)
__device__ inline void stage_tile(const float* __restrict__ src, size_t row0,
                                  int col0, int rowstride, bf (*dst)[LDK], int tid) {
  int r = tid >> 4, c4 = (tid & 15) * 4;
  #pragma unroll
  for (int it = 0; it < 4; ++it) {
    int row = r + it * 16;
    const float4 v = *(const float4*)&src[(row0 + row) * (size_t)rowstride + col0 + c4];
    union { bf h4[4]; short4 s4; } u;
    u.h4[0] = tobf(v.x); u.h4[1] = tobf(v.y); u.h4[2] = tobf(v.z); u.h4[3] = tobf(v.w);
    *(short4*)&dst[row][c4] = u.s4;
  }
}

// load this lane's A-fragments straight from the bf16 copy (two 16B loads)
__device__ inline void load_afrag_bf(const bf* __restrict__ arow, int quad, short8 af[2]) {
  af[0] = *(const short8*)&arow[quad * 8];
  af[1] = *(const short8*)&arow[32 + quad * 8];
}

// ---------------- conv body: grouped 1x1 conv + relu, dual write + rn + bf16 x-copy ----------------
__device__ inline void conv_body(
    char* SM, int m0, int g, int tid,
    const float* __restrict__ x, const float* __restrict__ w,
    const float* __restrict__ bias, const int* __restrict__ smask,
    float seedbase, float* __restrict__ out, float* __restrict__ out2,
    float* __restrict__ rn, bf* __restrict__ xbf) {
  float (*Xs)[65] = (float(*)[65])SM;
  float (*Wsm)[65] = (float(*)[65])(SM + 16640);
  const int tx = tid & 15, ty = tid >> 4;
  #pragma unroll
  for (int l = 0; l < 16; ++l) {
    int idx = tid + l * 256; int r = idx >> 6, c = idx & 63;
    Xs[r][c] = x[(size_t)(m0 + r) * CH + g * DK + c];
    Wsm[r][c] = w[g * DK * DK + r * DK + c];
  }
  __syncthreads();
  {  // bf16 copy of the input slice (node-major) for topk/apply staging
    int r = tid >> 4, c4 = (tid & 15) * 4;
    #pragma unroll
    for (int it = 0; it < 4; ++it) {
      int row = r + it * 16;
      union { bf h4[4]; short4 s4; } u;
      u.h4[0] = tobf(Xs[row][c4]);     u.h4[1] = tobf(Xs[row][c4 + 1]);
      u.h4[2] = tobf(Xs[row][c4 + 2]); u.h4[3] = tobf(Xs[row][c4 + 3]);
      *(short4*)&xbf[(size_t)(m0 + row) * CH + g * DK + c4] = u.s4;
    }
  }
  {  // fused reciprocal norms: 4 lanes per row, 16 channels each
    int wv = tid >> 6, lane = tid & 63;
    int row = wv * 16 + (lane >> 2), part = lane & 3;
    float s = 0.f;
    #pragma unroll
    for (int k = 0; k < 16; ++k) {
      float v = Xs[row][part * 16 + k];
      s += v * v;
    }
    s += __shfl_xor(s, 1, 64);
    s += __shfl_xor(s, 2, 64);
    if (part == 0)
      rn[(size_t)(m0 + row) * HEADS + g] = 1.0f / fmaxf(sqrtf(s), 1e-4f);
  }
  float acc[4][4] = {};
  #pragma unroll 8
  for (int k = 0; k < DK; ++k) {
    float av[4], bv[4];
    #pragma unroll
    for (int i = 0; i < 4; ++i) av[i] = Xs[ty * 4 + i][k];
    #pragma unroll
    for (int j = 0; j < 4; ++j) bv[j] = Wsm[tx * 4 + j][k];
    #pragma unroll
    for (int i = 0; i < 4; ++i)
      #pragma unroll
      for (int j = 0; j < 4; ++j) acc[i][j] += av[i] * bv[j];
  }
  #pragma unroll
  for (int i = 0; i < 4; ++i) {
    int row = m0 + ty * 4 + i;
    float seed = seedbase + ((smask[row] == 0) ? 0.25f : 0.f);
    #pragma unroll
    for (int j = 0; j < 4; ++j) {
      int o = g * DK + tx * 4 + j;
      size_t idx = (size_t)row * CH + o;
      float v = fmaxf(acc[i][j] + bias[o], 0.f);
      out[idx] = v;
      out2[idx] = v * seed;
    }
  }
}

// ---------------- gts body: relu(gt_feat @ gt_w^T + gt_b), bf16 MFMA ----------------
__device__ inline void gts_body(
    char* SM, int m0, int n0, int tid,
    const float* __restrict__ gf, const float* __restrict__ gw,
    const float* __restrict__ gb, float* __restrict__ out) {
  bf (*As)[LDK] = (bf(*)[LDK])SM;
  bf (*Bs)[LDK] = (bf(*)[LDK])(SM + 9216);
  const int lane = tid & 63, w = tid >> 6;
  const int m = lane & 15, quad = lane >> 4;
  f32x4 acc[4] = {{0.f,0.f,0.f,0.f},{0.f,0.f,0.f,0.f},{0.f,0.f,0.f,0.f},{0.f,0.f,0.f,0.f}};
  for (int k0 = 0; k0 < 256; k0 += 64) {
    __syncthreads();
    stage_tile(gf, m0, k0, 256, As, tid);
    stage_tile(gw, n0, k0, 256, Bs, tid);
    __syncthreads();
    #pragma unroll
    for (int kb = 0; kb < 2; ++kb) {
      short8 a = *(const short8*)&As[w * 16 + m][kb * 32 + quad * 8];
      #pragma unroll
      for (int nt = 0; nt < 4; ++nt) {
        short8 bb = *(const short8*)&Bs[nt * 16 + m][kb * 32 + quad * 8];
        acc[nt] = __builtin_amdgcn_mfma_f32_16x16x32_bf16(a, bb, acc[nt], 0, 0, 0);
      }
    }
  }
  #pragma unroll
  for (int nt = 0; nt < 4; ++nt)
    #pragma unroll
    for (int r = 0; r < 4; ++r) {
      int row = m0 + w * 16 + quad * 4 + r, col = n0 + nt * 16 + m;
      out[(size_t)row * 256 + col] = fmaxf(acc[nt][r] + gb[col], 0.f);
    }
}

// ================ mega head kernel: conv1 (y<4) | gts (y 4..7) | pack (y 8..23) ================
__global__ __launch_bounds__(256) void head_kernel(
    const float* __restrict__ x, const float* __restrict__ w1,
    const float* __restrict__ b1, const int* __restrict__ smask,
    float* __restrict__ X1, float* __restrict__ F1, float* __restrict__ rn,
    bf* __restrict__ xbf,
    const float* __restrict__ gf, const float* __restrict__ gw,
    const float* __restrict__ gb, float* __restrict__ gts_out,
    const int* __restrict__ mroi, u64* __restrict__ pk,
    float* __restrict__ v1, float* __restrict__ v2) {
  __shared__ __align__(16) char SM[33280];
  const int tid = threadIdx.x;
  if (blockIdx.y < 4) {
    conv_body(SM, blockIdx.x * 64, blockIdx.y, tid, x, w1, b1, smask, 1.0f, X1, F1, rn, xbf);
  } else if (blockIdx.y < 8) {
    gts_body(SM, blockIdx.x * 64, (blockIdx.y - 4) * 64, tid, gf, gw, gb, gts_out);
  } else {
    int blkrow = (blockIdx.y - 8) * 64 + blockIdx.x;   // 0..1023
    if (blkrow < 4) {
      int i = blkrow * 256 + tid;
      v1[i] = 0.f; v2[i] = 0.f;
    }
    int row = blkrow * 4 + (tid >> 6);
    int lane = tid & 63;
    int b = row >> 10;
    const int* mr = &mroi[(size_t)row * NUM];
    const int* sm = &smask[b * NUM];
    #pragma unroll
    for (int wd = 0; wd < 16; ++wd) {
      int j = wd * 64 + lane;
      u64 word = __ballot((mr[j] != 0) && (sm[j] != 0));
      if (lane == 0) pk[(size_t)row * 16 + wd] = word;
    }
  }
}

// ---------------- grouped 1x1 conv + relu (fp32) standalone (stage 2) ----------------
__global__ __launch_bounds__(256) void conv_kernel(
    const float* __restrict__ x, const float* __restrict__ w,
    const float* __restrict__ bias, const int* __restrict__ smask,
    float seedbase, float* __restrict__ out, float* __restrict__ out2,
    float* __restrict__ rn, bf* __restrict__ xbf) {
  __shared__ __align__(16) char SM[33280];
  conv_body(SM, blockIdx.x * 64, blockIdx.y, threadIdx.x, x, w, bias, smask,
            seedbase, out, out2, rn, xbf);
}

// top-4 insert, jax-stable tie-break (higher value first; equal value -> lower index)
__device__ inline void ins4(float v, int id, float tv[4], int tj[4]) {
  if (v < tv[3] || (v == tv[3] && id > tj[3])) return;
  tv[3] = v; tj[3] = id;
  #pragma unroll
  for (int k = 3; k > 0; --k) {
    bool sw = (tv[k] > tv[k - 1]) || (tv[k] == tv[k - 1] && tj[k] < tj[k - 1]);
    if (sw) {
      float fv = tv[k]; tv[k] = tv[k - 1]; tv[k - 1] = fv;
      int ti = tj[k]; tj[k] = tj[k - 1]; tj[k - 1] = ti;
    }
  }
}

// ---------------- per-row top-4 within a 256-col j-chunk (bf16 MFMA, bf16 staging) ----------------
// Ranking: v = relu(dot * rnj) -- same order & zero-ties as relu(dot/(ni*nj)).
__global__ __launch_bounds__(256) void topk_part_kernel(
    const bf* __restrict__ xbf, const float* __restrict__ rn,
    float* __restrict__ candV, int* __restrict__ candI) {
  __shared__ __align__(16) float cV[64][65];     // overlaid: Xj tile during j-loop
  __shared__ unsigned short cI[64][66];
  bf (*Xj)[LDK] = (bf(*)[LDK])cV;                // 9216 B <= 16640 B, safe overlay
  const int b = blockIdx.z, h = blockIdx.y;
  const int it = blockIdx.x >> 2, jc = blockIdx.x & 3;
  const int i0 = it * 64;
  const int tid = threadIdx.x, lane = tid & 63, w = tid >> 6;
  const int m = lane & 15, quad = lane >> 4;

  short8 afrag[2];
  load_afrag_bf(&xbf[((size_t)b * NUM + i0 + w * 16 + m) * CH + h * DK], quad, afrag);

  float tv[4][4]; int tj[4][4];
  #pragma unroll
  for (int r = 0; r < 4; ++r)
    #pragma unroll
    for (int q = 0; q < 4; ++q) { tv[r][q] = -1.f; tj[r][q] = 0xffff; }

  for (int jt = 0; jt < 4; ++jt) {
    int j0 = jc * 256 + jt * 64;
    __syncthreads();
    stage_tile_bf(xbf, (size_t)b * NUM + j0, h * DK, CH, Xj, tid);
    __syncthreads();
    #pragma unroll
    for (int nt = 0; nt < 4; ++nt) {
      f32x4 acc = {0.f, 0.f, 0.f, 0.f};
      #pragma unroll
      for (int kb = 0; kb < 2; ++kb) {
        short8 bb = *(const short8*)&Xj[nt * 16 + m][kb * 32 + quad * 8];
        acc = __builtin_amdgcn_mfma_f32_16x16x32_bf16(afrag[kb], bb, acc, 0, 0, 0);
      }
      int j = j0 + nt * 16 + m;
      float rnj = rn[((size_t)b * NUM + j) * HEADS + h];
      #pragma unroll
      for (int r = 0; r < 4; ++r) {
        float v = fmaxf(acc[r] * rnj, 0.f);
        ins4(v, j, tv[r], tj[r]);
      }
    }
  }
  __syncthreads();  // Xj dead; reuse memory as cV/cI
  #pragma unroll
  for (int r = 0; r < 4; ++r)
    #pragma unroll
    for (int q = 0; q < 4; ++q) {
      cV[w * 16 + quad * 4 + r][m * 4 + q] = tv[r][q];
      cI[w * 16 + quad * 4 + r][m * 4 + q] = (unsigned short)tj[r][q];
    }
  __syncthreads();
  if (tid < 64) {
    float fv[4] = {-1.f, -1.f, -1.f, -1.f};
    int fi[4] = {0x7fffffff, 0x7fffffff, 0x7fffffff, 0x7fffffff};
    for (int q = 0; q < 64; ++q) ins4(cV[tid][q], (int)cI[tid][q], fv, fi);
    size_t base = (size_t)((((b * HEADS + h) * 16 + it) * NJC + jc) * 64 + tid) * 4;
    #pragma unroll
    for (int q = 0; q < 4; ++q) { candV[base + q] = fv[q]; candI[base + q] = fi[q]; }
  }
}

// ---------------- merge NJC chunk candidates per row -> union into vec ----------------
__global__ __launch_bounds__(256) void topk_merge_kernel(
    const float* __restrict__ candV, const int* __restrict__ candI,
    float* __restrict__ vec) {
  int t = blockIdx.x * 256 + threadIdx.x;   // t = bhit*64 + rl
  int bhit = t >> 6, rl = t & 63;
  float fv[4] = {-1.f, -1.f, -1.f, -1.f};
  int fi[4] = {0x7fffffff, 0x7fffffff, 0x7fffffff, 0x7fffffff};
  #pragma unroll
  for (int jc = 0; jc < NJC; ++jc) {
    size_t base = (size_t)(((bhit) * NJC + jc) * 64 + rl) * 4;
    #pragma unroll
    for (int q = 0; q < 4; ++q) ins4(candV[base + q], candI[base + q], fv, fi);
  }
  #pragma unroll
  for (int q = 0; q < 4; ++q) vec[fi[q]] = 1.0f;  // benign race, all write 1
}

// ---------------- masked attention apply (bf16 MFMA scores + PV), j-chunked ----------------
// Norm factorization: relu(acc*rni*rnj) = rni*rnj*relu(acc). rnj*vec folded into Cv;
// rni*0.25 applied in the epilogue. Score loop: Ws = bit ? relu(acc) : 0 (no mults).
// Diagonal f_mask term is pre-seeded into `out` by conv. NJC=4: atomics bind.
__global__ __launch_bounds__(256) void apply_kernel(
    const bf* __restrict__ xbf, const float* __restrict__ conv,
    float* __restrict__ out, const float* __restrict__ rn,
    const float* __restrict__ vec, const u64* __restrict__ pk) {
  __shared__ __align__(16) bf Xj[64][LDK];
  __shared__ __align__(16) bf Cv[64][LDK];
  __shared__ __align__(16) bf Ws[64][LDK];
  const int b = blockIdx.z, h = blockIdx.y;
  const int it = blockIdx.x >> 2, jc = blockIdx.x & 3;
  const int i0 = it * 64;
  const int tid = threadIdx.x, lane = tid & 63, w = tid >> 6;
  const int m = lane & 15, quad = lane >> 4;

  short8 afrag[2];
  load_afrag_bf(&xbf[((size_t)b * NUM + i0 + w * 16 + m) * CH + h * DK], quad, afrag);

  float rni4[4];
  #pragma unroll
  for (int r = 0; r < 4; ++r) {
    int row = i0 + w * 16 + quad * 4 + r;
    rni4[r] = 0.25f * rn[((size_t)b * NUM + row) * HEADS + h];
  }
  f32x4 om[4] = {{0.f,0.f,0.f,0.f},{0.f,0.f,0.f,0.f},{0.f,0.f,0.f,0.f},{0.f,0.f,0.f,0.f}};

  for (int jt = 0; jt < 4; ++jt) {
    int j0 = jc * 256 + jt * 64;
    __syncthreads();   // protect Xj/Cv from previous iteration's readers
    stage_tile_bf(xbf, (size_t)b * NUM + j0, h * DK, CH, Xj, tid);
    {  // (vec*rnj)-scaled conv^T tile
      int jr = tid >> 4, c4 = tid & 15;
      #pragma unroll
      for (int itt = 0; itt < 4; ++itt) {
        int j = jr + itt * 16;
        float sc = vec[j0 + j] * rn[((size_t)b * NUM + j0 + j) * HEADS + h];
        const float4 v = *(const float4*)&conv[((size_t)b * NUM + j0 + j) * CH + h * DK + c4 * 4];
        Cv[c4 * 4 + 0][j] = tobf(v.x * sc);
        Cv[c4 * 4 + 1][j] = tobf(v.y * sc);
        Cv[c4 * 4 + 2][j] = tobf(v.z * sc);
        Cv[c4 * 4 + 3][j] = tobf(v.w * sc);
      }
    }
    u64 wr[4];
    #pragma unroll
    for (int r = 0; r < 4; ++r)
      wr[r] = pk[((size_t)b * NUM + i0 + w * 16 + quad * 4 + r) * 16 + (j0 >> 6)];
    __syncthreads();
    // scores -> masked weights -> Ws (own wave's 16-row stripe only)
    #pragma unroll
    for (int nt = 0; nt < 4; ++nt) {
      f32x4 acc = {0.f, 0.f, 0.f, 0.f};
      #pragma unroll
      for (int kb = 0; kb < 2; ++kb) {
        short8 bb = *(const short8*)&Xj[nt * 16 + m][kb * 32 + quad * 8];
        acc = __builtin_amdgcn_mfma_f32_16x16x32_bf16(afrag[kb], bb, acc, 0, 0, 0);
      }
      #pragma unroll
      for (int r = 0; r < 4; ++r) {
        bool bit = (wr[r] >> (nt * 16 + m)) & 1ull;
        Ws[w * 16 + quad * 4 + r][nt * 16 + m] = tobf(bit ? fmaxf(acc[r], 0.f) : 0.f);
      }
    }
    // PV: same-wave Ws stripe + Cv (stable until next loop-top barrier)
    #pragma unroll
    for (int kb = 0; kb < 2; ++kb) {
      short8 a = *(const short8*)&Ws[w * 16 + m][kb * 32 + quad * 8];
      #pragma unroll
      for (int ct = 0; ct < 4; ++ct) {
        short8 bb = *(const short8*)&Cv[ct * 16 + m][kb * 32 + quad * 8];
        om[ct] = __builtin_amdgcn_mfma_f32_16x16x32_bf16(a, bb, om[ct], 0, 0, 0);
      }
    }
  }
  #pragma unroll
  for (int ct = 0; ct < 4; ++ct)
    #pragma unroll
    for (int r = 0; r < 4; ++r) {
      size_t idx = ((size_t)b * NUM + i0 + w * 16 + quad * 4 + r) * CH + h * DK + ct * 16 + m;
      atomicAdd(&out[idx], om[ct][r] * rni4[r]);
    }
}

// ---------------- LayerNorm + final outputs (in-place on d_out regions) ----------------
__global__ __launch_bounds__(256) void final_kernel(
    float* __restrict__ ybnf, float* __restrict__ out0,
    const float* __restrict__ lnw, const float* __restrict__ lnb) {
  __shared__ float r1[4];
  __shared__ float r2[4];
  int bn = blockIdx.x;
  int c = threadIdx.x;
  size_t idx = (size_t)bn * CH + c;
  float y = ybnf[idx];
  float x2v = out0[idx];
  float s = y;
  #pragma unroll
  for (int off = 32; off; off >>= 1) s += __shfl_down(s, off, 64);
  int wave = c >> 6, lane = c & 63;
  if (lane == 0) r1[wave] = s;
  __syncthreads();
  float mu = (r1[0] + r1[1] + r1[2] + r1[3]) * (1.f / 256.f);
  float d = y - mu;
  float s2 = d * d;
  #pragma unroll
  for (int off = 32; off; off >>= 1) s2 += __shfl_down(s2, off, 64);
  if (lane == 0) r2[wave] = s2;
  __syncthreads();
  float var = (r2[0] + r2[1] + r2[2] + r2[3]) * (1.f / 256.f);
  float nf = d * rsqrtf(var + 1e-6f) * lnw[c] + lnb[c];
  ybnf[idx] = nf;
  out0[idx] = x2v + nf;
}

extern "C" void kernel_launch(void* const* d_in, const int* in_sizes, int n_in,
                              void* d_out, int out_size, void* d_ws, size_t ws_size,
                              hipStream_t stream) {
  const float* input = (const float*)d_in[0];
  const int* mroi = (const int*)d_in[1];
  const int* smask = (const int*)d_in[2];
  const float* gt_feat = (const float*)d_in[3];
  const float* w1 = (const float*)d_in[4];
  const float* b1 = (const float*)d_in[5];
  const float* w2 = (const float*)d_in[6];
  const float* b2 = (const float*)d_in[7];
  const float* gt_w = (const float*)d_in[8];
  const float* gt_b = (const float*)d_in[9];
  const float* lnw = (const float*)d_in[10];
  const float* lnb = (const float*)d_in[11];

  const size_t SEG = (size_t)B_ * NUM * CH;  // 1048576 elements
  float* out0 = (float*)d_out;     // finally: out2^T + node_feat ; interim: X2 (conv2)
  float* gts = out0 + SEG;         // gts output (final from the start)
  float* nfreg = out0 + 2 * SEG;   // finally: node_feat ; interim: X1 then Yb

  // ws: F1 4MB | RN 64KB | VEC 8KB | candV 1MB | candI 1MB | PK 512KB | XBF 2MB ~= 8.6 MB
  float* F1 = (float*)d_ws;
  float* RN = F1 + SEG;
  float* VEC1 = RN + (size_t)B_ * NUM * HEADS;
  float* VEC2 = VEC1 + NUM;
  float* candV = VEC2 + NUM;
  const size_t NCAND = (size_t)B_ * HEADS * 16 * NJC * 64 * 4;
  int* candI = (int*)(candV + NCAND);
  u64* PK = (u64*)(candI + NCAND);
  bf* XBF = (bf*)(PK + (size_t)B_ * NUM * 16);  // bf16 copy of stage input

  float* X1 = nfreg;  // conv1 output (F1 seeded = X1*(1+0.25*[sm==0]))
  float* X2 = out0;   // conv2 output lives in out0 region until final_kernel
  float* Yb = nfreg;  // o2m accumulator (seeded = 0.25*[sm==0]*X2, overwrites dead X1)

  // fused: conv1+xbf (y<4) + gts (y 4..7) + pack/vec-zero (y 8..23)
  head_kernel<<<dim3(64, 24), 256, 0, stream>>>(
      input, w1, b1, smask, X1, F1, RN, XBF,
      gt_feat, gt_w, gt_b, gts, mroi, PK, VEC1, VEC2);

  // stage 1
  topk_part_kernel<<<dim3(16 * NJC, HEADS, B_), 256, 0, stream>>>(XBF, RN, candV, candI);
  topk_merge_kernel<<<64, 256, 0, stream>>>(candV, candI, VEC1);
  apply_kernel<<<dim3(16 * NJC, HEADS, B_), 256, 0, stream>>>(
      XBF, X1, F1, RN, VEC1, PK);

  // stage 2 (conv2 also refreshes XBF with bf16(F1))
  conv_kernel<<<dim3(64, 4), 256, 0, stream>>>(F1, w2, b2, smask, 0.0f, X2, Yb, RN, XBF);
  topk_part_kernel<<<dim3(16 * NJC, HEADS, B_), 256, 0, stream>>>(XBF, RN, candV, candI);
  topk_merge_kernel<<<64, 256, 0, stream>>>(candV, candI, VEC2);
  apply_kernel<<<dim3(16 * NJC, HEADS, B_), 256, 0, stream>>>(
      XBF, X2, Yb, RN, VEC2, PK);

  final_kernel<<<4096, 256, 0, stream>>>(Yb, X2, lnw, lnb);
}